// Round 5
// baseline (772.491 us; speedup 1.0000x reference)
//
#include <hip/hip_runtime.h>
#include <cmath>

// Problem constants
#define S_LEN 2048
#define HID 4096
#define NHEAD 32
#define Q_LORA 1536
#define KV_LORA 512
#define NOPE 128
#define ROPE_D 64
#define VDIM 128
#define QK_DIM 192       // NOPE + ROPE
#define FUSED_N 2112     // Q_LORA + KV_LORA + ROPE
#define FUSED_NPAD 2176  // padded to a multiple of 128

typedef __attribute__((ext_vector_type(8))) short short8;
typedef __attribute__((ext_vector_type(4))) float floatx4;
typedef unsigned short ushort_t;

// float -> bf16 bits, round-to-nearest-even
__device__ inline short f2bf(float f) {
    union { float f; unsigned u; } v; v.f = f;
    unsigned r = (v.u + 0x7fffu + ((v.u >> 16) & 1u)) >> 16;
    return (short)r;
}
__device__ inline float bf2f(ushort_t u) {
    union { unsigned u; float f; } v; v.u = ((unsigned)u) << 16; return v.f;
}

// async 16B global -> LDS (LDS dest: wave-uniform base + lane*16)
#define GLOAD16(g, l)                                                        \
    __builtin_amdgcn_global_load_lds(                                        \
        (const __attribute__((address_space(1))) unsigned int*)(g),          \
        (__attribute__((address_space(3))) unsigned int*)(l), 16, 0, 0)

__device__ inline short8 conv8(const float* s) {
    const float4* s4 = (const float4*)s;
    float4 a = s4[0], b = s4[1];
    short8 v;
    v[0] = f2bf(a.x); v[1] = f2bf(a.y); v[2] = f2bf(a.z); v[3] = f2bf(a.w);
    v[4] = f2bf(b.x); v[5] = f2bf(b.y); v[6] = f2bf(b.z); v[7] = f2bf(b.w);
    return v;
}

// ---------------------------------------------------------------------------
// Merged fp32->bf16 conversion of hs, w_a (padded), w_qb, w_kvb — 1 dispatch.
// ---------------------------------------------------------------------------
#define CE0 (S_LEN * HID)                    //  8388608  hs
#define CE1 (CE0 + FUSED_NPAD * HID)         // +8912896  w_a padded
#define CE2 (CE1 + NHEAD * QK_DIM * Q_LORA)  // +9437184  w_qb
#define CE3 (CE2 + NHEAD * 256 * KV_LORA)    // +4194304  w_kvb

__global__ __launch_bounds__(256) void conv_all(
    const float* __restrict__ hs, const float* __restrict__ w_a,
    const float* __restrict__ w_qb, const float* __restrict__ w_kvb,
    ushort_t* __restrict__ hs_bf, ushort_t* __restrict__ w_a_bf,
    ushort_t* __restrict__ w_qb_bf, ushort_t* __restrict__ w_kvb_bf)
{
    int i = (blockIdx.x * 256 + threadIdx.x) * 8;
    if (i < CE0) {
        *(short8*)(hs_bf + i) = conv8(hs + i);
    } else if (i < CE1) {
        int j = i - CE0;
        short8 v;
        if (j < FUSED_N * HID) v = conv8(w_a + j);
        else                   v = (short8){0,0,0,0,0,0,0,0};
        *(short8*)(w_a_bf + j) = v;
    } else if (i < CE2) {
        int j = i - CE1;
        *(short8*)(w_qb_bf + j) = conv8(w_qb + j);
    } else if (i < CE3) {
        int j = i - CE2;
        *(short8*)(w_kvb_bf + j) = conv8(w_kvb + j);
    }
}

// plain converter (used for w_o after gemm1 frees its region)
__global__ __launch_bounds__(256) void conv_bf16(
    const float* __restrict__ src, ushort_t* __restrict__ dst, int n)
{
    int i = (blockIdx.x * 256 + threadIdx.x) * 8;
    if (i >= n) return;
    *(short8*)(dst + i) = conv8(src + i);
}

// ---------------------------------------------------------------------------
// fp32 pairwise add (split-K reduce): o = p0 + p1
// ---------------------------------------------------------------------------
__global__ __launch_bounds__(256) void reduce_add_f32(
    const float* __restrict__ p0, const float* __restrict__ p1,
    float* __restrict__ o, int n)
{
    int i = (blockIdx.x * 256 + threadIdx.x) * 4;
    if (i >= n) return;
    float4 a = *(const float4*)(p0 + i);
    float4 b = *(const float4*)(p1 + i);
    float4 c; c.x = a.x + b.x; c.y = a.y + b.y; c.z = a.z + b.z; c.w = a.w + b.w;
    *(float4*)(o + i) = c;
}

// ---------------------------------------------------------------------------
// bf16 MFMA GEMM body, 2-phase pipelined: acc += A(M,K) * B(N,K)^T tile.
// 128x128 tile, BK=32, 4 waves 2x2. LDS fragment-order [rb:8][quad:4][lane:16].
// ---------------------------------------------------------------------------
__device__ __forceinline__ void gemm_body(
    const ushort_t* __restrict__ A, int lda,
    const ushort_t* __restrict__ B, int ldb,
    int m0, int n0, int kbeg, int kend,
    short8* As8, short8* Bs8,             // each [2][512] flattened
    floatx4 (&acc)[4][4], int tid)
{
    const int lane = tid & 63;
    const int wave = tid >> 6;
    const int m    = lane & 15;
    const int quad = lane >> 4;
    const int wr   = wave >> 1, wc = wave & 1;

    const int R0 = tid >> 6, q0s = (tid >> 4) & 3, e0 = tid & 15;
    const int R1 = (tid + 256) >> 6, q1s = ((tid + 256) >> 4) & 3, e1 = (tid + 256) & 15;

    auto stage = [&](int k0, int buf) {
        GLOAD16(A + (size_t)(m0 + R0 * 16 + e0) * lda + k0 + q0s * 8, &As8[buf * 512 + tid]);
        GLOAD16(A + (size_t)(m0 + R1 * 16 + e1) * lda + k0 + q1s * 8, &As8[buf * 512 + tid + 256]);
        GLOAD16(B + (size_t)(n0 + R0 * 16 + e0) * ldb + k0 + q0s * 8, &Bs8[buf * 512 + tid]);
        GLOAD16(B + (size_t)(n0 + R1 * 16 + e1) * ldb + k0 + q1s * 8, &Bs8[buf * 512 + tid + 256]);
    };

    stage(kbeg, 0);
    __syncthreads();
    int cur = 0;

    for (int k0 = kbeg; k0 < kend; k0 += 32) {
        if (k0 + 32 < kend) stage(k0 + 32, cur ^ 1);

        short8 af[4], bfr[4];
        #pragma unroll
        for (int i = 0; i < 4; ++i) af[i]  = As8[cur * 512 + ((wr * 4 + i) * 4 + quad) * 16 + m];
        #pragma unroll
        for (int i = 0; i < 4; ++i) bfr[i] = Bs8[cur * 512 + ((wc * 4 + i) * 4 + quad) * 16 + m];

        #pragma unroll
        for (int ri = 0; ri < 4; ++ri)
            #pragma unroll
            for (int ci = 0; ci < 4; ++ci)
                acc[ri][ci] = __builtin_amdgcn_mfma_f32_16x16x32_bf16(
                    af[ri], bfr[ci], acc[ri][ci], 0, 0, 0);

        __syncthreads();   // drains vmcnt+lgkm: next buf ready, cur reads done
        cur ^= 1;
    }
}

__device__ inline void store_c(float* p, float v)    { *p = v; }
__device__ inline void store_c(ushort_t* p, float v) { *p = (ushort_t)f2bf(v); }

template <typename CT>
__device__ __forceinline__ void gemm_store(
    CT* __restrict__ C, int ldc, int N, int m0, int n0,
    floatx4 (&acc)[4][4], int tid)
{
    const int lane = tid & 63;
    const int wave = tid >> 6;
    const int m    = lane & 15;
    const int quad = lane >> 4;
    const int wr   = wave >> 1, wc = wave & 1;
    #pragma unroll
    for (int ci = 0; ci < 4; ++ci) {
        int col = n0 + wc * 64 + ci * 16 + m;
        if (col < N) {
            #pragma unroll
            for (int ri = 0; ri < 4; ++ri) {
                int row = m0 + wr * 64 + ri * 16 + quad * 4;
                #pragma unroll
                for (int r = 0; r < 4; ++r)
                    store_c(&C[(size_t)(row + r) * ldc + col], acc[ri][ci][r]);
            }
        }
    }
}

// generic GEMM with optional split-K via blockIdx.z (C-plane per z)
template <typename CT>
__global__ __launch_bounds__(256) void gemm_bf16(
    const ushort_t* __restrict__ A, int lda,
    const ushort_t* __restrict__ B, int ldb,
    CT* __restrict__ C, int ldc, int N, int Klen)
{
    __shared__ short8 As8[2 * 512];   // 16 KB
    __shared__ short8 Bs8[2 * 512];   // 16 KB
    const int tid = threadIdx.x;
    const int m0 = blockIdx.y * 128;
    const int n0 = blockIdx.x * 128;
    const int kbeg = blockIdx.z * Klen;
    CT* Cz = C + (size_t)blockIdx.z * (size_t)gridDim.y * 128 * ldc;

    floatx4 acc[4][4];
    #pragma unroll
    for (int i = 0; i < 4; ++i)
        #pragma unroll
        for (int j = 0; j < 4; ++j) acc[i][j] = (floatx4){0.f, 0.f, 0.f, 0.f};

    gemm_body(A, lda, B, ldb, m0, n0, kbeg, kbeg + Klen, As8, Bs8, acc, tid);
    gemm_store<CT>(Cz, ldc, N, m0, n0, acc, tid);
}

// merged gemm3 (q = cq @ w_qb^T, N=6144, K=1536) + gemm4 (kv = ckv @ w_kvb^T,
// N=8192, K=512) — one dispatch, blocks x<48 are gemm3, rest gemm4.
__global__ __launch_bounds__(256) void gemm34(
    const ushort_t* __restrict__ a_bf,
    const ushort_t* __restrict__ w_qb_bf,
    const ushort_t* __restrict__ w_kvb_bf,
    ushort_t* __restrict__ q_bf,
    ushort_t* __restrict__ kv_bf)
{
    __shared__ short8 As8[2 * 512];
    __shared__ short8 Bs8[2 * 512];
    const int tid = threadIdx.x;
    const int x = blockIdx.x;
    const int m0 = blockIdx.y * 128;

    const ushort_t* A; const ushort_t* B; ushort_t* C;
    int ldb, ldc, N, K, n0;
    if (x < 48) {   // gemm3
        A = a_bf;            B = w_qb_bf;  C = q_bf;
        ldb = Q_LORA;        ldc = NHEAD * QK_DIM; N = NHEAD * QK_DIM;
        K = Q_LORA;          n0 = x * 128;
    } else {        // gemm4
        A = a_bf + Q_LORA;   B = w_kvb_bf; C = kv_bf;
        ldb = KV_LORA;       ldc = NHEAD * 256;    N = NHEAD * 256;
        K = KV_LORA;         n0 = (x - 48) * 128;
    }

    floatx4 acc[4][4];
    #pragma unroll
    for (int i = 0; i < 4; ++i)
        #pragma unroll
        for (int j = 0; j < 4; ++j) acc[i][j] = (floatx4){0.f, 0.f, 0.f, 0.f};

    gemm_body(A, FUSED_N, B, ldb, m0, n0, 0, K, As8, Bs8, acc, tid);
    gemm_store<ushort_t>(C, ldc, N, m0, n0, acc, tid);
}

// ---------------------------------------------------------------------------
// Fused split-K reduce + RMSNorm(cq), RMSNorm(ckv) + RoPE(k_pe).
// part: 2 fp32 planes of (S, FUSED_N); output a: bf16 (S, FUSED_N).
// ln-weights indexed RELATIVE to segment.
// ---------------------------------------------------------------------------
__global__ __launch_bounds__(256) void norm_rope_kernel(
    const float* __restrict__ part,
    ushort_t* __restrict__ a,
    const float* __restrict__ q_ln_w,
    const float* __restrict__ kv_ln_w,
    const int* __restrict__ pos_ids)
{
    const int s = blockIdx.x;
    const float* r0 = part + (size_t)s * FUSED_N;
    const float* r1 = part + (size_t)S_LEN * FUSED_N + (size_t)s * FUSED_N;
    ushort_t* row = a + (size_t)s * FUSED_N;
    __shared__ float red[256];
    const int tid = threadIdx.x;

    float vq[6];
    float ss = 0.f;
    #pragma unroll
    for (int j = 0; j < 6; ++j) {
        int i = tid + j * 256;
        vq[j] = r0[i] + r1[i];
        ss += vq[j] * vq[j];
    }
    red[tid] = ss;
    __syncthreads();
    for (int w = 128; w > 0; w >>= 1) {
        if (tid < w) red[tid] += red[tid + w];
        __syncthreads();
    }
    float scale_q = rsqrtf(red[0] / (float)Q_LORA + 1e-6f);
    #pragma unroll
    for (int j = 0; j < 6; ++j) {
        int i = tid + j * 256;
        row[i] = (ushort_t)f2bf(vq[j] * scale_q * q_ln_w[i]);
    }
    __syncthreads();

    float vk[2];
    ss = 0.f;
    #pragma unroll
    for (int j = 0; j < 2; ++j) {
        int iw = tid + j * 256;
        vk[j] = r0[Q_LORA + iw] + r1[Q_LORA + iw];
        ss += vk[j] * vk[j];
    }
    red[tid] = ss;
    __syncthreads();
    for (int w = 128; w > 0; w >>= 1) {
        if (tid < w) red[tid] += red[tid + w];
        __syncthreads();
    }
    float scale_kv = rsqrtf(red[0] / (float)KV_LORA + 1e-6f);
    #pragma unroll
    for (int j = 0; j < 2; ++j) {
        int iw = tid + j * 256;
        row[Q_LORA + iw] = (ushort_t)f2bf(vk[j] * scale_kv * kv_ln_w[iw]);
    }

    if (tid < 32) {
        const int j = tid;
        float pos = (float)pos_ids[s];
        float inv_freq = expf(-(float)j * (9.210340371976184f / 32.f));
        float ang = pos * inv_freq;
        float c = cosf(ang), sn = sinf(ang);
        float x1 = r0[Q_LORA + KV_LORA + j]      + r1[Q_LORA + KV_LORA + j];
        float x2 = r0[Q_LORA + KV_LORA + 32 + j] + r1[Q_LORA + KV_LORA + 32 + j];
        row[Q_LORA + KV_LORA + j]      = (ushort_t)f2bf(x1 * c - x2 * sn);
        row[Q_LORA + KV_LORA + 32 + j] = (ushort_t)f2bf(x2 * c + x1 * sn);
    }
}

// ---------------------------------------------------------------------------
// RoPE on q_pe (bf16 in place): q is (S*H, 192), rope dims [128,192)
// ---------------------------------------------------------------------------
__global__ __launch_bounds__(256) void rope_q_kernel(
    ushort_t* __restrict__ q, const int* __restrict__ pos_ids)
{
    int idx = blockIdx.x * blockDim.x + threadIdx.x;
    if (idx >= S_LEN * NHEAD) return;
    int s = idx >> 5;
    float pos = (float)pos_ids[s];
    ushort_t* qp = q + (size_t)idx * QK_DIM + NOPE;
    #pragma unroll 4
    for (int j = 0; j < 32; ++j) {
        float inv_freq = expf(-(float)j * (9.210340371976184f / 32.f));
        float ang = pos * inv_freq;
        float c = cosf(ang), sn = sinf(ang);
        float x1 = bf2f(qp[j]), x2 = bf2f(qp[32 + j]);
        qp[j]      = (ushort_t)f2bf(x1 * c - x2 * sn);
        qp[32 + j] = (ushort_t)f2bf(x2 * c + x1 * sn);
    }
}

// ---------------------------------------------------------------------------
// V pre-transpose: kv (S, H, 256) bf16, v part [128,256) -> vt blocked
// (H, S/8, 128, 8) bf16:  vt[h][g][d][j] = v[key = g*8+j][d]
// ---------------------------------------------------------------------------
__global__ __launch_bounds__(256) void transpose_v(
    const ushort_t* __restrict__ kv, ushort_t* __restrict__ vt)
{
    __shared__ ushort_t vs[32][128];   // 8 KB
    const int tid = threadIdx.x;
    const int h   = blockIdx.y;
    const int kb  = blockIdx.x;        // block of 32 keys

    #pragma unroll
    for (int rep = 0; rep < 2; ++rep) {
        int i = rep * 256 + tid;
        int key = i >> 4, ch = i & 15;
        *(short8*)&vs[key][ch * 8] =
            *(const short8*)(kv + ((size_t)(kb * 32 + key) * NHEAD + h) * 256 + 128 + ch * 8);
    }
    __syncthreads();
    #pragma unroll
    for (int rep = 0; rep < 2; ++rep) {
        int i = rep * 256 + tid;
        int kq = i >> 7, d = i & 127;
        short8 v;
        #pragma unroll
        for (int j = 0; j < 8; ++j) v[j] = vs[kq * 8 + j][d];
        *(short8*)(vt + (((size_t)h * (S_LEN / 8) + kb * 4 + kq) * 128 + d) * 8) = v;
    }
}

// ---------------------------------------------------------------------------
// MFMA bf16 flash attention (causal), 2-phase pipelined + balanced + KV-split.
//   Block (pair p, head h, eta): q-tiles {31-p, p}; for q-tile qt with
//   ntile=2(qt+1) key-tiles, eta=0 handles tiles [0, qt+1), eta=1 the rest
//   -> exactly 33 key-tile units per block, 1024 blocks.
//   Writes UNNORMALIZED partial O (bf16) + per-row (m, l) for the combine.
// ---------------------------------------------------------------------------
__global__ __launch_bounds__(256) void attn_mfma(
    const ushort_t* __restrict__ q,
    const ushort_t* __restrict__ kv,
    const ushort_t* __restrict__ abuf,
    const ushort_t* __restrict__ vt,
    ushort_t* __restrict__ part,      // (h, qt, eta, 64, 128) bf16
    float2* __restrict__ ml)          // (h, qt, eta, 64)
{
    __shared__ short8 KF[2][768];   // 24 KB
    __shared__ short8 VF[2][512];   // 16 KB
    __shared__ short8 PA[256];      //  4 KB

    const int tid  = threadIdx.x;
    const int wave = tid >> 6;
    const int lane = tid & 63;
    const int m    = lane & 15;
    const int quad = lane >> 4;
    const int h    = blockIdx.y;
    const int pair = blockIdx.x;                  // 0..15
    const int eta  = blockIdx.z;                  // 0..1
    const int qtiles[2] = { 31 - pair, pair };    // big tile first

    const float scale = 0.07216878364870323f; // 1/sqrt(192)
    short* pas = (short*)PA;

    auto stage_kv = [&](int t0, int buf) {
        #pragma unroll
        for (int rep = 0; rep < 3; ++rep) {
            int i   = rep * 256 + tid;
            int key = i & 31, qd = (i >> 5) & 3, c = i >> 7;   // c wave-uniform
            if (c < 4)
                GLOAD16(kv + ((size_t)(t0 + key) * NHEAD + h) * 256 + c * 32 + qd * 8,
                        &KF[buf][i]);
            else
                GLOAD16(abuf + (size_t)(t0 + key) * FUSED_N + 2048 + (c - 4) * 32 + qd * 8,
                        &KF[buf][i]);
        }
        const ushort_t* vsrc = vt + ((size_t)h * (S_LEN / 8) + (t0 >> 3)) * 1024;
        GLOAD16(vsrc + (size_t)tid * 8, &VF[buf][tid]);
        GLOAD16(vsrc + (size_t)(256 + tid) * 8, &VF[buf][256 + tid]);
    };

    for (int qi = 0; qi < 2; ++qi) {
        const int qt = qtiles[qi];
        const int q0 = qt * 64;
        const int qrow_base = q0 + wave * 16;

        short8 qf[6];
        {
            const ushort_t* qrow = q + ((size_t)(qrow_base + m) * NHEAD + h) * QK_DIM;
            #pragma unroll
            for (int c = 0; c < 6; ++c)
                qf[c] = *(const short8*)(qrow + c * 32 + quad * 8);
        }

        floatx4 O[8];
        #pragma unroll
        for (int t = 0; t < 8; ++t) O[t] = (floatx4){0.f, 0.f, 0.f, 0.f};
        float mrow[4] = {-1e30f, -1e30f, -1e30f, -1e30f};
        float lrow[4] = {0.f, 0.f, 0.f, 0.f};

        // eta=0: key-tiles [0, qt+1); eta=1: [qt+1, 2qt+2)
        const int tbeg = eta ? (qt + 1) : 0;
        const int tend = eta ? (2 * qt + 2) : (qt + 1);

        stage_kv(tbeg * 32, 0);
        __syncthreads();
        int cur = 0;

        for (int tt = tbeg; tt < tend; ++tt) {
            const int t0 = tt * 32;
            if (tt + 1 < tend) stage_kv(t0 + 32, cur ^ 1);

            floatx4 s0 = (floatx4){0.f, 0.f, 0.f, 0.f};
            floatx4 s1 = (floatx4){0.f, 0.f, 0.f, 0.f};
            const int kb = quad * 32 + m;
            __builtin_amdgcn_s_setprio(1);
            #pragma unroll
            for (int c = 0; c < 6; ++c) {
                s0 = __builtin_amdgcn_mfma_f32_16x16x32_bf16(qf[c], KF[cur][c * 128 + kb],      s0, 0, 0, 0);
                s1 = __builtin_amdgcn_mfma_f32_16x16x32_bf16(qf[c], KF[cur][c * 128 + kb + 16], s1, 0, 0, 0);
            }
            __builtin_amdgcn_s_setprio(0);

            const int qb = qrow_base + quad * 4;
            float sv0[4], sv1[4];
            #pragma unroll
            for (int r = 0; r < 4; ++r) {
                float a0 = s0[r] * scale;
                float a1 = s1[r] * scale;
                if (t0 + m > qb + r)      a0 = -1e30f;
                if (t0 + 16 + m > qb + r) a1 = -1e30f;
                sv0[r] = a0; sv1[r] = a1;
            }
            #pragma unroll
            for (int r = 0; r < 4; ++r) {
                float v = fmaxf(sv0[r], sv1[r]);
                v = fmaxf(v, __shfl_xor(v, 1));
                v = fmaxf(v, __shfl_xor(v, 2));
                v = fmaxf(v, __shfl_xor(v, 4));
                v = fmaxf(v, __shfl_xor(v, 8));
                // defer-max (THR=8): P bounded by e^8, bf16-safe.
                if (v > mrow[r] + 8.f) {
                    float alpha = __expf(mrow[r] - v);   // first real tile: ->0
                    lrow[r] *= alpha;
                    #pragma unroll
                    for (int t = 0; t < 8; ++t) O[t][r] *= alpha;
                    mrow[r] = v;
                }
                float p0 = __expf(sv0[r] - mrow[r]);
                float p1 = __expf(sv1[r] - mrow[r]);
                lrow[r] += p0 + p1;                      // per-lane partial
                int row = quad * 4 + r;
                short* pw = pas + wave * 512;
                pw[((m >> 3) + 0) * 128 + row * 8 + (m & 7)] = f2bf(p0);
                pw[((m >> 3) + 2) * 128 + row * 8 + (m & 7)] = f2bf(p1);
            }

            short8 pfrag = PA[wave * 64 + quad * 16 + m];
            __builtin_amdgcn_s_setprio(1);
            #pragma unroll
            for (int t = 0; t < 8; ++t) {
                O[t] = __builtin_amdgcn_mfma_f32_16x16x32_bf16(
                    pfrag, VF[cur][quad * 128 + m + 16 * t], O[t], 0, 0, 0);
            }
            __builtin_amdgcn_s_setprio(0);

            __syncthreads();   // drains vmcnt+lgkm: next buf staged, cur reads done
            cur ^= 1;
        }

        // partial epilogue: unnormalized O (bf16) + (m, l) per row
        const int slot = (h * 32 + qt) * 2 + eta;
        #pragma unroll
        for (int r = 0; r < 4; ++r) {
            float l = lrow[r];
            l += __shfl_xor(l, 1);
            l += __shfl_xor(l, 2);
            l += __shfl_xor(l, 4);
            l += __shfl_xor(l, 8);
            int rr = wave * 16 + quad * 4 + r;
            ushort_t* dst = part + ((size_t)slot * 64 + rr) * 128 + m;
            #pragma unroll
            for (int t = 0; t < 8; ++t)
                dst[16 * t] = (ushort_t)f2bf(O[t][r]);
            if (m == 0) ml[slot * 64 + rr] = make_float2(mrow[r], l);
        }
    }
}

// ---------------------------------------------------------------------------
// Combine the two KV-half partials:  O = (w0*O0 + w1*O1) / (w0*l0 + w1*l1),
// wi = exp(mi - max(m0,m1)).  Fully-masked halves have m=-1e30 -> weight 0.
// ---------------------------------------------------------------------------
__global__ __launch_bounds__(256) void attn_combine(
    const ushort_t* __restrict__ part,   // (h, qt, eta, 64, 128) bf16
    const float2* __restrict__ ml,       // (h, qt, eta, 64)
    ushort_t* __restrict__ attn)         // (s, h, 128) bf16
{
    int gid = blockIdx.x * 256 + threadIdx.x;
    int row = gid >> 4;                  // h*2048 + qt*64 + rr
    int dch = (gid & 15) * 8;
    int h  = row >> 11;
    int qr = row & 2047;
    int qt = qr >> 6, rr = qr & 63;
    int slot = (h * 32 + qt) * 2;

    float2 ml0 = ml[(slot + 0) * 64 + rr];
    float2 ml1 = ml[(slot + 1) * 64 + rr];
    float M  = fmaxf(ml0.x, ml1.x);
    float w0 = __expf(ml0.x - M);
    float w1 = __expf(ml1.x - M);
    float inv = 1.f / (w0 * ml0.y + w1 * ml1.y);

    short8 a = *(const short8*)(part + ((size_t)(slot + 0) * 64 + rr) * 128 + dch);
    short8 b = *(const short8*)(part + ((size_t)(slot + 1) * 64 + rr) * 128 + dch);
    short8 o;
    #pragma unroll
    for (int j = 0; j < 8; ++j)
        o[j] = f2bf((w0 * bf2f((ushort_t)a[j]) + w1 * bf2f((ushort_t)b[j])) * inv);

    int s = qr;   // qt*64 + rr
    *(short8*)(attn + ((size_t)s * NHEAD + h) * VDIM + dch) = o;
}

// ---------------------------------------------------------------------------
extern "C" void kernel_launch(void* const* d_in, const int* in_sizes, int n_in,
                              void* d_out, int out_size, void* d_ws, size_t ws_size,
                              hipStream_t stream)
{
    const int*   pos    = (const int*)d_in[0];
    const float* hs     = (const float*)d_in[1];
    const float* w_a    = (const float*)d_in[2];
    const float* qlnw   = (const float*)d_in[3];
    const float* kvlnw  = (const float*)d_in[4];
    const float* w_qb   = (const float*)d_in[5];
    const float* w_kvb  = (const float*)d_in[6];
    const float* w_o    = (const float*)d_in[7];
    float* out = (float*)d_out;

    // workspace layout — 146.0 MB total (unchanged from round 2/4)
    char* p = (char*)d_ws;
    ushort_t* a_bf    = (ushort_t*)p; p += (size_t)S_LEN * FUSED_N * 2;          //  8.65 MB
    ushort_t* q_bf    = (ushort_t*)p; p += (size_t)S_LEN * NHEAD * QK_DIM * 2;   // 25.2 MB
    ushort_t* kv_bf   = (ushort_t*)p; p += (size_t)S_LEN * NHEAD * 256 * 2;      // 33.6 MB
    ushort_t* attn_bf = (ushort_t*)p; p += (size_t)S_LEN * HID * 2;              // 16.8 MB
    ushort_t* hs_bf   = (ushort_t*)p; p += (size_t)S_LEN * HID * 2;              // 16.8 MB
    ushort_t* w_a_bf  = (ushort_t*)p; p += (size_t)FUSED_NPAD * HID * 2;         // 17.8 MB
    ushort_t* w_qb_bf = (ushort_t*)p; p += (size_t)NHEAD * QK_DIM * Q_LORA * 2;  // 18.9 MB
    ushort_t* w_kvb_bf= (ushort_t*)p; p += (size_t)NHEAD * 256 * KV_LORA * 2;    //  8.4 MB
    // w_o_bf (33.6 MB) aliases hs_bf + w_a_bf, both dead after gemm 1
    ushort_t* w_o_bf  = hs_bf;
    // vt (16.8 MB) aliases w_qb_bf (18.9 MB), dead after gemm 3
    ushort_t* vt_bf   = w_qb_bf;
    // gemm1 split-K fp32 partials (34.6 MB) in q_bf+kv_bf region
    float* part1 = (float*)q_bf;
    // gemm7 split-K fp32 partials (67.1 MB) in a_bf+q_bf+kv_bf region
    float* part7 = (float*)a_bf;
    // attn partial O (33.55 MB bf16) lives in d_out (dead until gemm7/reduce);
    // per-row (m,l) (1 MB) in w_kvb region (dead after gemm34).
    ushort_t* attn_part = (ushort_t*)d_out;
    float2*   attn_ml   = (float2*)w_kvb_bf;

    if (ws_size < (size_t)(p - (char*)d_ws)) return;  // fail loud, not fault

    dim3 blk(256);
    auto cgrid = [](size_t n) { return dim3((unsigned)((n / 8 + 255) / 256)); };

    // 0. merged fp32 -> bf16 (hs, w_a pad, w_qb, w_kvb) — one dispatch
    conv_all<<<dim3(CE3 / 2048), blk, 0, stream>>>(
        hs, w_a, w_qb, w_kvb, hs_bf, w_a_bf, w_qb_bf, w_kvb_bf);

    // 1. a = hs @ w_fused_a^T : split-K=2, fp32 partials (2048, 2112) x2
    gemm_bf16<float><<<dim3(FUSED_NPAD / 128, S_LEN / 128, 2), blk, 0, stream>>>(
        hs_bf, HID, w_a_bf, HID, part1, FUSED_N, FUSED_N, HID / 2);

    // 1b. w_o -> bf16 (into region freed by gemm 1)
    conv_bf16<<<cgrid((size_t)HID * HID), blk, 0, stream>>>(w_o, w_o_bf, HID * HID);

    // 2. fused split-K reduce + RMSNorm cq/ckv + k_pe RoPE -> a_bf
    norm_rope_kernel<<<S_LEN, 256, 0, stream>>>(part1, a_bf, qlnw, kvlnw, pos);

    // 3+4. merged q/kv projection GEMMs (1792 blocks, one dispatch)
    gemm34<<<dim3(48 + 64, S_LEN / 128), blk, 0, stream>>>(
        a_bf, w_qb_bf, w_kvb_bf, q_bf, kv_bf);

    // 4b. V pre-transpose into blocked (H, S/8, 128, 8) — w_qb region now dead
    transpose_v<<<dim3(S_LEN / 32, NHEAD), blk, 0, stream>>>(kv_bf, vt_bf);

    // 5. RoPE on q_pe (bf16 in place)
    rope_q_kernel<<<(S_LEN * NHEAD + 255) / 256, 256, 0, stream>>>(q_bf, pos);

    // 6. MFMA flash attention, KV-split=2 -> partials in d_out + (m,l)
    attn_mfma<<<dim3(16, NHEAD, 2), blk, 0, stream>>>(
        q_bf, kv_bf, a_bf, vt_bf, attn_part, attn_ml);

    // 6b. combine partials -> attn (2048, 32, 128) bf16
    attn_combine<<<dim3(NHEAD * S_LEN * 16 / 256), blk, 0, stream>>>(
        attn_part, attn_ml, attn_bf);

    // 7. out = attn @ w_o^T : split-K=2, fp32 partials (2048, 4096) x2, then add
    gemm_bf16<float><<<dim3(HID / 128, S_LEN / 128, 2), blk, 0, stream>>>(
        attn_bf, HID, w_o_bf, HID, part7, HID, HID, HID / 2);
    reduce_add_f32<<<cgrid((size_t)S_LEN * HID * 2), blk, 0, stream>>>(
        part7, part7 + (size_t)S_LEN * HID, out, S_LEN * HID);
}